// Round 5
// baseline (65.837 us; speedup 1.0000x reference)
//
#include <hip/hip_runtime.h>

// DepthLoss3D: N=4096 (16x16x16), all-pairs masked manhattan -> 3 scalars.
//
// Structure (R9): single fused dispatch. 3 channels x 136 triangular
// (gi>=gj) group-pairs x 256x256 elems, each task split 2 ways in x ->
// 816 blocks (R8 used SPLIT=4/1632 blocks; R9 tests the per-WG-overhead
// hypothesis: halve dispatch+setup instances, same total VALU).
// steps = sc*(gi-gj) is block-uniform; gi<gj pairs are exactly zero
// (skipped); gi==gj is 0.5*|dm| via symmetry.
//
// Inner loop (R8's proven 6 VALU/pair): identity
//     f(d) = max3(d-s, 0.2s-d, 0) - 0.2s*[d<0]     (s >= 0)
// verified vs reference where-chain: d<0 -> max3 = 0.2s-d dominates, minus
// 0.2s gives -d; 0<=d<0.2s -> 0.2s-d; 0.2s<=d<s -> 0; d>=s -> d-s; s==0
// (diagonal) -> |d|, count term vanishes. x is a per-thread REGISTER
// (a=x-s, b=0.2s-x once per thread), y read from LDS with wave-uniform
// float4 address (same-address broadcast, conflict-free).
// Per pair: t1=a-y, t2=b+y, v_max3, acc+=, v_cmp(y>x), v_addc -> 6 VALU.
// (y>x) == exact (d<0): fp sub preserves sign.
//
// Wave mapping (SPLIT=2): block covers x in [part*128,(part+1)*128) x all
// 256 y. Wave w: x-half (w&1) -> x = part*128+(w&1)*64+lane; y-half (w>>1)
// -> 32 float4 LDS reads per thread, 128 pairs/thread.
//
// Reduction: each block stores its partial (clamped >=0 -> SIGN BIT CLEAR)
// as one 32-bit word via relaxed agent-scope atomic into d_ws; 0xAAAAAAAA
// poison has the sign bit SET, so sign-clear == ready — the value is its
// own flag. Block 0 polls all 816 words (serial poll; R7's vectorized poll
// was neutral: poll is off the critical path), reduces per channel, writes
// d_out. No finalize dispatch, no counter (R6: single fetch_add counter
// cost +31us — 1632 same-address agent RMWs serialize ~19ns each).

#define BLOCK 256
#define NTASK_PER_CH 136               // 16*17/2 triangular group pairs
#define SPLIT 2                        // x-split per task
#define NBLK (3 * NTASK_PER_CH * SPLIT)    // 816
#define PER_CH (NTASK_PER_CH * SPLIT)      // 272 partials per channel

__device__ __forceinline__ int elem_index(int c, int g, int k) {
    // flat (h,w,d) index whose c-th nibble is g, other two nibbles from k
    const int kh = k >> 4, kl = k & 15;
    if (c == 0) return (g << 8) | k;
    if (c == 1) return (kh << 8) | (g << 4) | kl;
    return (kh << 8) | (kl << 4) | g;
}

__global__ __launch_bounds__(BLOCK) void depth_loss_fused(
        const float* __restrict__ pred,
        const float* __restrict__ spac,
        float* __restrict__ partial /* [NBLK] in d_ws */,
        float* __restrict__ out) {
    const int tid  = threadIdx.x;
    const int blk  = blockIdx.x;
    const int task = blk >> 1;          // / SPLIT
    const int part = blk & 1;
    const int c    = (task >= 2 * NTASK_PER_CH) ? 2
                   : (task >= NTASK_PER_CH)     ? 1 : 0;
    int r = task - c * NTASK_PER_CH;

    // triangular decode: row gi has gi+1 entries (gj = 0..gi); uniform loop
    int gi = 0;
    while (r >= gi + 1) { r -= gi + 1; ++gi; }
    const int gj = r;

    const float sc    = spac[c] * 2.0f;                 // spacing * STEP
    const float s     = (float)(gi - gj) * sc;          // block-uniform step
    const float s02   = 0.2f * s;
    const float scale = (gi == gj) ? 0.5f : 1.0f;

    const int lane = tid & 63;
    const int wave = tid >> 6;
    const int xh   = wave & 1;          // x-half within the block's 128 x's
    const int yv   = wave >> 1;         // y-half of the 256 y's

    // all 256 y's of group gj -> LDS; x -> register
    __shared__ float4 ys4[64];
    ((float*)ys4)[tid] = pred[3 * elem_index(c, gj, tid) + c];
    const float x = pred[3 * elem_index(c, gi, part * 128 + xh * 64 + lane) + c];
    const float a = x - s;        // t1 = a - y == d - s
    const float b = s02 - x;      // t2 = b + y == 0.2s - d
    __syncthreads();

    const float4* yb = &ys4[yv * 32];   // wave-uniform base -> broadcast reads
    float acc0 = 0.0f, acc1 = 0.0f;
    unsigned cnt = 0;                    // # pairs with d<0  (y > x)
#pragma unroll
    for (int i = 0; i < 32; ++i) {
        const float4 y4 = yb[i];         // same-address across wave: conflict-free
        acc0 += fmaxf(fmaxf(a - y4.x, b + y4.x), 0.0f);  // v_max3
        cnt  += (y4.x > x);
        acc1 += fmaxf(fmaxf(a - y4.y, b + y4.y), 0.0f);
        cnt  += (y4.y > x);
        acc0 += fmaxf(fmaxf(a - y4.z, b + y4.z), 0.0f);
        cnt  += (y4.z > x);
        acc1 += fmaxf(fmaxf(a - y4.w, b + y4.w), 0.0f);
        cnt  += (y4.w > x);
    }
    float acc = fmaf(-s02, (float)cnt, acc0 + acc1) * scale;

    // wave butterfly -> cross-wave LDS -> one word store per block
    for (int off = 32; off > 0; off >>= 1) acc += __shfl_down(acc, off, 64);
    __shared__ float wsum[BLOCK / 64];
    if ((tid & 63) == 0) wsum[wave] = acc;
    __syncthreads();
    if (tid == 0) {
        float t = 0.0f;
#pragma unroll
        for (int w = 0; w < BLOCK / 64; ++w) t += wsum[w];
        t = fmaxf(t, 0.0f);              // clamp: sign bit clear == ready
        __hip_atomic_store(&partial[blk], t, __ATOMIC_RELAXED,
                           __HIP_MEMORY_SCOPE_AGENT);
    }

    if (blk != 0) return;

    // ---- block 0: poll + final reduce (value doubles as ready-flag) ----
    float a0 = 0.0f, a1 = 0.0f, a2 = 0.0f;
    for (int sidx = tid; sidx < NBLK; sidx += BLOCK) {   // <=4 chains
        float v;
        do {
            v = __hip_atomic_load(&partial[sidx], __ATOMIC_RELAXED,
                                  __HIP_MEMORY_SCOPE_AGENT);
        } while (__float_as_uint(v) >> 31);   // poison is negative; data >= 0
        if (sidx >= 2 * PER_CH)      a2 += v;
        else if (sidx >= PER_CH)     a1 += v;
        else                         a0 += v;
    }
    for (int off = 32; off > 0; off >>= 1) {
        a0 += __shfl_down(a0, off, 64);
        a1 += __shfl_down(a1, off, 64);
        a2 += __shfl_down(a2, off, 64);
    }
    __shared__ float fin[3][BLOCK / 64];
    __syncthreads();                          // LDS reuse barrier
    if ((tid & 63) == 0) { fin[0][wave] = a0; fin[1][wave] = a1; fin[2][wave] = a2; }
    __syncthreads();
    if (tid == 0) {
        float t0 = 0.0f, t1 = 0.0f, t2 = 0.0f;
#pragma unroll
        for (int w = 0; w < BLOCK / 64; ++w) {
            t0 += fin[0][w]; t1 += fin[1][w]; t2 += fin[2][w];
        }
        const float inv = 1.0f / (4096.0f * 4096.0f);
        out[0] = t0 * inv;   // overwrites 0xAA poison
        out[1] = t1 * inv;
        out[2] = t2 * inv;
    }
}

extern "C" void kernel_launch(void* const* d_in, const int* in_sizes, int n_in,
                              void* d_out, int out_size, void* d_ws, size_t ws_size,
                              hipStream_t stream) {
    const float* pred = (const float*)d_in[0];   // [4096,3] fp32
    const float* spac = (const float*)d_in[1];   // [3,1]   fp32
    depth_loss_fused<<<NBLK, BLOCK, 0, stream>>>(pred, spac,
                                                 (float*)d_ws, (float*)d_out);
}